// Round 4
// baseline (419.972 us; speedup 1.0000x reference)
//
#include <hip/hip_runtime.h>
#include <stdint.h>

#define SEQ    4096
#define HID    2048
#define NQKV   6144
#define QKW    4096   // width of the QK row-major buffer (Q | K)
#define NH     16
#define HD     128
#define SCALE  0.08838834764831845f
#define GQC    32     // split-KV chunks for global-query path (128 kv each)

typedef unsigned short u16;
typedef __attribute__((ext_vector_type(8))) short bf16x8;
typedef __attribute__((ext_vector_type(4))) float f32x4;

__device__ __forceinline__ u16 f2bf(float f) {
  union { float f; unsigned u; } v; v.f = f;
  unsigned r = v.u + 0x7FFFu + ((v.u >> 16) & 1u);
  return (u16)(r >> 16);
}

__device__ __forceinline__ float bf2f(u16 b) {
  union { unsigned u; float f; } c; c.u = ((unsigned)b) << 16; return c.f;
}

__device__ __forceinline__ void async16(const u16* g, u16* l) {
  __builtin_amdgcn_global_load_lds(
      (const __attribute__((address_space(1))) unsigned int*)g,
      (__attribute__((address_space(3))) unsigned int*)l, 16, 0, 0);
}

// ---------------- prep: X->bf16 convert + 4 weight transposes + counter zero ----------------
__global__ __launch_bounds__(256) void prep(const float* __restrict__ X,
                                            const float* __restrict__ W0,
                                            const float* __restrict__ W1,
                                            const float* __restrict__ W2,
                                            const float* __restrict__ W3,
                                            u16* __restrict__ Xbf,
                                            u16* __restrict__ Wcat,
                                            u16* __restrict__ Wot,
                                            unsigned* __restrict__ cnt) {
  const int bx = blockIdx.x;
  const int t = threadIdx.x;
  if (bx == 0 && t < NH) cnt[t] = 0u;     // zero split-K completion counters
  if (bx < 8192) {
    int i = bx * 256 + t;
    float4 v = ((const float4*)X)[i];
    ushort4 o;
    o.x = f2bf(v.x); o.y = f2bf(v.y); o.z = f2bf(v.z); o.w = f2bf(v.w);
    ((ushort4*)Xbf)[i] = o;
    return;
  }
  __shared__ __align__(16) u16 Ts[64 * 68];
  const int b = bx - 8192;
  const int z = b >> 10;
  const int k0 = ((b >> 5) & 31) * 64;
  const int n0 = (b & 31) * 64;
  const float* W = (z == 0) ? W0 : (z == 1) ? W1 : (z == 2) ? W2 : W3;
  u16* Wt = (z < 3) ? (Wcat + (size_t)z * 2048 * 2048) : Wot;
#pragma unroll
  for (int p = 0; p < 4; ++p) {
    int f = (t + p * 256) * 4;
    int r = f >> 6, c = f & 63;            // r=k_local, c=n_local
    float4 v = *(const float4*)&W[(size_t)(k0 + r) * 2048 + n0 + c];
    ushort4 o; o.x = f2bf(v.x); o.y = f2bf(v.y); o.z = f2bf(v.z); o.w = f2bf(v.w);
    *(ushort4*)&Ts[r * 68 + c] = o;
  }
  __syncthreads();
#pragma unroll
  for (int p = 0; p < 4; ++p) {
    int g = (t + p * 256) * 4;
    int r = g >> 6, c = g & 63;            // r=n_local, c=k_local
    ushort4 o;
    o.x = Ts[(c + 0) * 68 + r];
    o.y = Ts[(c + 1) * 68 + r];
    o.z = Ts[(c + 2) * 68 + r];
    o.w = Ts[(c + 3) * 68 + r];
    *(ushort4*)&Wt[(size_t)(n0 + r) * 2048 + k0 + c] = o;
  }
}

// ---------------- old 128x128 GEMM (kept for the output projection) ----------------
template <typename OutT, bool WVT>
__global__ __launch_bounds__(256) void gemm_bt(const u16* __restrict__ A,
                                               const u16* __restrict__ B,
                                               OutT* __restrict__ C,
                                               u16* __restrict__ VTout,
                                               int K, int ldc) {
  __shared__ __align__(16) u16 As0[128 * 32];
  __shared__ __align__(16) u16 As1[128 * 32];
  __shared__ __align__(16) u16 Bs0[128 * 32];
  __shared__ __align__(16) u16 Bs1[128 * 32];
  const int m0 = blockIdx.y * 128;
  const int n0 = blockIdx.x * 128;
  const int tid = threadIdx.x;
  const int wid = tid >> 6;
  const int lane = tid & 63;
  const int wm = wid & 1, wn = wid >> 1;
  const int l15 = lane & 15, g4 = lane >> 4;

  const int srow = wid * 32 + (lane >> 2);
  const int scol = (lane & 3) * 8;

  f32x4 acc[4][4] = {};

  const u16* pa0 = &A[(size_t)(m0 + srow) * K + scol];
  const u16* pa1 = &A[(size_t)(m0 + srow + 16) * K + scol];
  const u16* pb0 = &B[(size_t)(n0 + srow) * K + scol];
  const u16* pb1 = &B[(size_t)(n0 + srow + 16) * K + scol];
  const int lo0 = (wid * 32) * 32, lo1 = (wid * 32 + 16) * 32;

  for (int kt = 0; kt < K; kt += 64) {
    __syncthreads();
    async16(pa0 + kt, &As0[lo0]);
    async16(pa1 + kt, &As0[lo1]);
    async16(pb0 + kt, &Bs0[lo0]);
    async16(pb1 + kt, &Bs0[lo1]);
    async16(pa0 + kt + 32, &As1[lo0]);
    async16(pa1 + kt + 32, &As1[lo1]);
    async16(pb0 + kt + 32, &Bs1[lo0]);
    async16(pb1 + kt + 32, &Bs1[lo1]);
    __syncthreads();
    {
      bf16x8 af[4], bfr[4];
#pragma unroll
      for (int i = 0; i < 4; ++i)
        af[i] = *(const bf16x8*)&As0[(wm * 64 + i * 16 + l15) * 32 + g4 * 8];
#pragma unroll
      for (int i = 0; i < 4; ++i)
        bfr[i] = *(const bf16x8*)&Bs0[(wn * 64 + i * 16 + l15) * 32 + g4 * 8];
#pragma unroll
      for (int mi = 0; mi < 4; ++mi)
#pragma unroll
        for (int ni = 0; ni < 4; ++ni)
          acc[mi][ni] = __builtin_amdgcn_mfma_f32_16x16x32_bf16(af[mi], bfr[ni], acc[mi][ni], 0, 0, 0);
    }
    {
      bf16x8 af[4], bfr[4];
#pragma unroll
      for (int i = 0; i < 4; ++i)
        af[i] = *(const bf16x8*)&As1[(wm * 64 + i * 16 + l15) * 32 + g4 * 8];
#pragma unroll
      for (int i = 0; i < 4; ++i)
        bfr[i] = *(const bf16x8*)&Bs1[(wn * 64 + i * 16 + l15) * 32 + g4 * 8];
#pragma unroll
      for (int mi = 0; mi < 4; ++mi)
#pragma unroll
        for (int ni = 0; ni < 4; ++ni)
          acc[mi][ni] = __builtin_amdgcn_mfma_f32_16x16x32_bf16(af[mi], bfr[ni], acc[mi][ni], 0, 0, 0);
    }
  }

  // C/D layout (m89): col = lane&15, row = (lane>>4)*4 + reg
  if (WVT && n0 >= QKW) {
#pragma unroll
    for (int mi = 0; mi < 4; ++mi)
#pragma unroll
      for (int ni = 0; ni < 4; ++ni) {
        const int nv = n0 - QKW + wn * 64 + ni * 16 + l15;
        const int hh = nv >> 7, dd = nv & 127;
        u16* base = &VTout[((size_t)hh * HD + dd) * SEQ];
        const int mb = m0 + wm * 64 + mi * 16 + g4 * 4;
        u16 pk[4];
#pragma unroll
        for (int r = 0; r < 4; ++r) pk[r] = f2bf(acc[mi][ni][r]);
        *(uint2*)&base[mb] = *(uint2*)pk;
      }
  } else {
#pragma unroll
    for (int mi = 0; mi < 4; ++mi)
#pragma unroll
      for (int ni = 0; ni < 4; ++ni) {
        const int n = n0 + wn * 64 + ni * 16 + l15;
#pragma unroll
        for (int r = 0; r < 4; ++r) {
          const int m = m0 + wm * 64 + mi * 16 + g4 * 4 + r;
          float v = acc[mi][ni][r];
          if constexpr (sizeof(OutT) == 2) {
            C[(size_t)m * ldc + n] = (OutT)f2bf(v);
          } else {
            C[(size_t)m * ldc + n] = v;
          }
        }
      }
  }
}

// ---------------- 256x256 8-phase GEMM, R4: read-ahead pipelined ----------------
// R3 post-mortem: [reads; barrier; lgkmcnt(0); MFMA; barrier] serializes the
// LDS burst with MFMA -> 4823 cyc/K-tile measured (= 2300 LDS + 2483 MFMA +
// barriers, model exact). R4: each phase body issues the NEXT phase's fragment
// reads; gate after the barrier is a COUNTED lgkmcnt(N_just_issued) so this
// phase's operands (read last phase, serviced during last MFMA) are waited
// while the new reads overlap this phase's MFMA. Reads balanced 4/8/8/4 per
// phase via quadrant order q00,q01,q11,q10 -> A/B fragments fit 2 register
// sets each (aX/aY, bU/bV; 96 VGPR, same as R3 -> no spill).
// Uniform vmcnt(6) per phase end (2 loads/phase, depth-3 pipeline):
// stage@p guaranteed complete at end of p+3; ledger:
//  stage:  ph1 B(tA)h1->Bs11  ph2 A(tA)h1->As11  ph3 A(tB)h0->As00
//          ph4 B(tB)h0->Bs00  ph5 B(tB)h1->Bs01  ph6 A(tB)h1->As01
//          ph7 A(tC)h0->As10  ph8 B(tC)h0->Bs10
//  read:   ph1 bV<-Bs01(g ph8-)  ph2 aY<-As01(g ph1-)  ph3 aX<-As10(g ph2-)
//          ph4 bV<-Bs10(g ph3-)  ph5 bU<-Bs11(g ph4-)  ph6 aY<-As11(g ph5-)
//          ph7 aX<-As00(g ph6-)  ph8 bU<-Bs00(g ph7-)   (g = guaranteed by)
//  every read-issue >=1 phase after its slot's guarantee; every stage lands
//  >=4 phases after the slot's last read-issue (WAR safe).
// lgkm gates (just-issued reads left outstanding): 4,8,8,12,4,8,8,12.
__device__ __forceinline__ void mfma16q(f32x4 (&q)[4][2],
                                        const bf16x8 (&a)[4][2],
                                        const bf16x8 (&b)[2][2]) {
#pragma unroll
  for (int fm = 0; fm < 4; ++fm)
#pragma unroll
    for (int fn = 0; fn < 2; ++fn) {
      q[fm][fn] = __builtin_amdgcn_mfma_f32_16x16x32_bf16(a[fm][0], b[fn][0], q[fm][fn], 0, 0, 0);
      q[fm][fn] = __builtin_amdgcn_mfma_f32_16x16x32_bf16(a[fm][1], b[fn][1], q[fm][fn], 0, 0, 0);
    }
}

#define PH(RD_STMT, SRC, HALF, TILE, SLOT, NLG, ACCQ, ASET, BSET)      \
  do {                                                                  \
    RD_STMT;                                                            \
    stage(SRC, HALF, TILE, SLOT);                                       \
    asm volatile("" ::: "memory");                                      \
    __builtin_amdgcn_s_barrier();                                       \
    asm volatile("s_waitcnt lgkmcnt(" #NLG ")" ::: "memory");           \
    __builtin_amdgcn_sched_barrier(0);                                  \
    __builtin_amdgcn_s_setprio(1);                                      \
    mfma16q(ACCQ, ASET, BSET);                                          \
    __builtin_amdgcn_s_setprio(0);                                      \
    asm volatile("s_waitcnt vmcnt(6)" ::: "memory");                    \
    asm volatile("" ::: "memory");                                      \
    __builtin_amdgcn_s_barrier();                                       \
  } while (0)

template <typename OutT, bool WVT>
__global__ __launch_bounds__(512, 2) void gemm256(const u16* __restrict__ A,
                                                  const u16* __restrict__ B,
                                                  OutT* __restrict__ C,
                                                  u16* __restrict__ VTout,
                                                  int K, int ldc) {
  __shared__ __align__(16) u16 As[2][2][128 * 64];
  __shared__ __align__(16) u16 Bs[2][2][128 * 64];
  const int m0 = blockIdx.y * 256;
  const int n0 = blockIdx.x * 256;
  const int tid = threadIdx.x;
  const int lane = tid & 63;
  const int wid = tid >> 6;
  const int wm = wid >> 2, wn = wid & 3;   // 2 M-waves x 4 N-waves
  const int l15 = lane & 15, g4 = lane >> 4;

  // staging: wave w instruction j covers LDS bytes [j*8192 + w*1024 + lane*16);
  // (row = j*64 + tid>>3, phys_slot = tid&7); logical slot = phys ^ (row&7)
  // -> inverse-swizzled on the per-lane global src (rule 21).
  const int r0 = tid >> 3;
  const int csw = ((tid & 7) ^ (r0 & 7)) * 8;      // (r+64)&7 == r&7, same for j=1
  const u16* Ag = A + (size_t)(m0 + r0) * K + csw;
  const u16* Bg = B + (size_t)(n0 + r0) * K + csw;

  // fragment read bases (u16 units): row rr*64 + ((logslot ^ (rr&7))<<3)
  const int aoff0 = (wm * 64 + l15) * 64;
  const int boff0 = (wn * 32 + l15) * 64;
  const int c0 = ((g4 ^ (l15 & 7)) << 3);          // ks=0: logslot = g4
  const int c1 = (((4 + g4) ^ (l15 & 7)) << 3);    // ks=1: logslot = 4+g4

  auto stage = [&](const u16* src, int half, int tile, u16* dst) {
    const u16* s = src + (size_t)half * 128 * K + (size_t)tile * 64;
    u16* d = dst + wid * 512;      // WAVE-UNIFORM LDS base; HW adds lane*16B
    async16(s, d);
    async16(s + (size_t)64 * K, d + 4096);
  };
  auto rdA = [&](const u16* h, bf16x8 (&a)[4][2]) {
#pragma unroll
    for (int fm = 0; fm < 4; ++fm) {
      a[fm][0] = *(const bf16x8*)&h[aoff0 + fm * 1024 + c0];
      a[fm][1] = *(const bf16x8*)&h[aoff0 + fm * 1024 + c1];
    }
  };
  auto rdB = [&](const u16* h, bf16x8 (&b)[2][2]) {
#pragma unroll
    for (int fn = 0; fn < 2; ++fn) {
      b[fn][0] = *(const bf16x8*)&h[boff0 + fn * 1024 + c0];
      b[fn][1] = *(const bf16x8*)&h[boff0 + fn * 1024 + c1];
    }
  };

  f32x4 acc[2][2][4][2] = {};
  bf16x8 aX[4][2], aY[4][2], bU[2][2], bV[2][2];

  // prologue: P1 a0, P2 b0, P3 b1, P4 a1, P5 a0', P6 b0' (12 loads);
  // vmcnt(6) completes P1-P3 (collective after barrier); pre-read a0,b0.
  stage(Ag, 0, 0, &As[0][0][0]);
  stage(Bg, 0, 0, &Bs[0][0][0]);
  stage(Bg, 1, 0, &Bs[0][1][0]);
  stage(Ag, 1, 0, &As[0][1][0]);
  stage(Ag, 0, 1, &As[1][0][0]);
  stage(Bg, 0, 1, &Bs[1][0][0]);
  asm volatile("s_waitcnt vmcnt(6)" ::: "memory");
  asm volatile("" ::: "memory");
  __builtin_amdgcn_s_barrier();
  rdA(&As[0][0][0], aX);
  rdB(&Bs[0][0][0], bU);

  const int NT = K >> 6;                 // 32 K-tiles of 64
  for (int it = 0; it < (NT >> 1); ++it) {
    const int tA = 2 * it + 1;
    const int tB = (2 * it + 2) & (NT - 1);
    const int tC = (2 * it + 3) & (NT - 1);   // wraps harmlessly on last iter
    // T0 (buf0), quadrants q00,q01,q11,q10
    PH(rdB(&Bs[0][1][0], bV), Bg, 1, tA, &Bs[1][1][0], 4,  acc[0][0], aX, bU);
    PH(rdA(&As[0][1][0], aY), Ag, 1, tA, &As[1][1][0], 8,  acc[0][1], aX, bV);
    PH(rdA(&As[1][0][0], aX), Ag, 0, tB, &As[0][0][0], 8,  acc[1][1], aY, bV);
    PH(rdB(&Bs[1][0][0], bV), Bg, 0, tB, &Bs[0][0][0], 12, acc[1][0], aY, bU);
    // T1 (buf1)
    PH(rdB(&Bs[1][1][0], bU), Bg, 1, tB, &Bs[0][1][0], 4,  acc[0][0], aX, bV);
    PH(rdA(&As[1][1][0], aY), Ag, 1, tB, &As[0][1][0], 8,  acc[0][1], aX, bU);
    PH(rdA(&As[0][0][0], aX), Ag, 0, tC, &As[1][0][0], 8,  acc[1][1], aY, bU);
    PH(rdB(&Bs[0][0][0], bU), Bg, 0, tC, &Bs[1][0][0], 12, acc[1][0], aY, bV);
  }
  // drain wrap-staged DMAs + pending wrap reads before epilogue/exit
  asm volatile("s_waitcnt vmcnt(0) lgkmcnt(0)" ::: "memory");

  // C/D layout (m89): col = lane&15, row = (lane>>4)*4 + reg
  if (WVT && n0 >= QKW) {
#pragma unroll
    for (int qm = 0; qm < 2; ++qm)
#pragma unroll
      for (int qn = 0; qn < 2; ++qn)
#pragma unroll
        for (int fm = 0; fm < 4; ++fm)
#pragma unroll
          for (int fn = 0; fn < 2; ++fn) {
            const int nv = n0 - QKW + qn * 128 + wn * 32 + fn * 16 + l15;
            const int hh = nv >> 7, dd = nv & 127;
            u16* base = &VTout[((size_t)hh * HD + dd) * SEQ];
            const int mb = m0 + qm * 128 + wm * 64 + fm * 16 + g4 * 4;
            u16 pk[4];
#pragma unroll
            for (int r = 0; r < 4; ++r) pk[r] = f2bf(acc[qm][qn][fm][fn][r]);
            *(uint2*)&base[mb] = *(uint2*)pk;
          }
  } else {
#pragma unroll
    for (int qm = 0; qm < 2; ++qm)
#pragma unroll
      for (int qn = 0; qn < 2; ++qn)
#pragma unroll
        for (int fm = 0; fm < 4; ++fm)
#pragma unroll
          for (int fn = 0; fn < 2; ++fn) {
            const int n = n0 + qn * 128 + wn * 32 + fn * 16 + l15;
#pragma unroll
            for (int r = 0; r < 4; ++r) {
              const int m = m0 + qm * 128 + wm * 64 + fm * 16 + g4 * 4 + r;
              float v = acc[qm][qn][fm][fn][r];
              if constexpr (sizeof(OutT) == 2) {
                C[(size_t)m * ldc + n] = (OutT)f2bf(v);
              } else {
                C[(size_t)m * ldc + n] = v;
              }
            }
          }
  }
}

// ---------------- fused attention dispatch ----------------
__global__ __launch_bounds__(256, 2) void attn_fused(const u16* __restrict__ qk,
                                                     const u16* __restrict__ vt,
                                                     u16* __restrict__ out,
                                                     float* __restrict__ Opart,
                                                     float* __restrict__ MLpart,
                                                     unsigned* __restrict__ cnt) {
  __shared__ __align__(16) u16 smem[24576];   // 48 KB, overlaid per path
  __shared__ unsigned lastflag;
  const int h = blockIdx.y;
  const int tid = threadIdx.x;
  const int lane = tid & 63;

  if (blockIdx.x < 32) {
    // ---------------- local path ----------------
    u16* Ks  = smem;            // [64 kv][128 d] swizzled, 16 KB
    u16* VTs = smem + 8192;     // [128 d][64 kv] swizzled, 16 KB
    u16* Ps  = smem + 16384;    // [128 q][64 kv] swizzled, wave-private rows, 16 KB
    const int q0 = blockIdx.x * 128;
    const int w = tid >> 6;
    const int l15 = lane & 15, g4 = lane >> 4, l7 = lane & 7;

    bf16x8 qf[2][4];
#pragma unroll
    for (int qs = 0; qs < 2; ++qs) {
      const u16* qrow = &qk[(size_t)(q0 + w * 32 + qs * 16 + l15) * QKW + h * HD + g4 * 8];
#pragma unroll
      for (int kk = 0; kk < 4; ++kk) qf[qs][kk] = *(const bf16x8*)&qrow[kk * 32];
    }

    float m_run[2] = {-1e30f, -1e30f}, l_run[2] = {0.f, 0.f};
    f32x4 o[2][8] = {};

    int lo = q0 - 255;
    int lo_blk = (lo < 0) ? 0 : (lo >> 6);
    int hi_blk = (q0 + 382) >> 6;
    if (hi_blk > 63) hi_blk = 63;
    const int extra = (lo_blk > 0) ? 1 : 0;
    const int nsteps = hi_blk - lo_blk + 1 + extra;

    for (int step = 0; step < nsteps; ++step) {
      const int kb = (extra && step == 0) ? 0 : (lo_blk + step - extra);
      const int kv0 = kb * 64;
      __syncthreads();
#pragma unroll
      for (int p = 0; p < 4; ++p) {
        const int r = w * 16 + p * 4 + (lane >> 4);
        const u16* src = &qk[(size_t)(kv0 + r) * QKW + 2048 + h * HD + (((lane & 15) ^ (r & 15)) * 8)];
        async16(src, &Ks[(w * 16 + p * 4) * 128]);
      }
#pragma unroll
      for (int p = 0; p < 4; ++p) {
        const int r = w * 32 + p * 8 + (lane >> 3);
        const u16* src = &vt[(size_t)h * (HD * SEQ) + (size_t)r * SEQ + kv0 + (((lane & 7) ^ (r & 7)) * 8)];
        async16(src, &VTs[(w * 32 + p * 8) * 64]);
      }
      __syncthreads();

      f32x4 st[2][4] = {};
#pragma unroll
      for (int kk = 0; kk < 4; ++kk) {
        bf16x8 ak[4];
#pragma unroll
        for (int t4 = 0; t4 < 4; ++t4)
          ak[t4] = *(const bf16x8*)&Ks[(t4 * 16 + l15) * 128 + (((kk * 4 + g4) ^ l15) * 8)];
#pragma unroll
        for (int qs = 0; qs < 2; ++qs)
#pragma unroll
          for (int t4 = 0; t4 < 4; ++t4)
            st[qs][t4] = __builtin_amdgcn_mfma_f32_16x16x32_bf16(ak[t4], qf[qs][kk], st[qs][t4], 0, 0, 0);
      }

#pragma unroll
      for (int qs = 0; qs < 2; ++qs) {
        const int q = q0 + w * 32 + qs * 16 + l15;
        float cmax = -1e30f;
#pragma unroll
        for (int t4 = 0; t4 < 4; ++t4)
#pragma unroll
          for (int r = 0; r < 4; ++r) {
            int kv = kv0 + t4 * 16 + g4 * 4 + r;
            int dq = q - kv; if (dq < 0) dq = -dq;
            bool ok = (dq < 256) || (kv < 16);
            float s = ok ? st[qs][t4][r] * SCALE : -1e30f;
            st[qs][t4][r] = s;
            cmax = fmaxf(cmax, s);
          }
        cmax = fmaxf(cmax, __shfl_xor(cmax, 16, 64));
        cmax = fmaxf(cmax, __shfl_xor(cmax, 32, 64));
        float mnew = fmaxf(m_run[qs], cmax);
        float csum = 0.f;
#pragma unroll
        for (int t4 = 0; t4 < 4; ++t4)
#pragma unroll
          for (int r = 0; r < 4; ++r) {
            float p = __expf(st[qs][t4][r] - mnew);
            st[qs][t4][r] = p;
            csum += p;
          }
        csum += __shfl_xor(csum, 16, 64);
        csum += __shfl_xor(csum, 32, 64);
        float a = __expf(m_run[qs] - mnew);
        m_run[qs] = mnew;
        l_run[qs] = l_run[qs] * a + csum;

#pragma unroll
        for (int t4 = 0; t4 < 4; ++t4) {
          u16 pk[4];
#pragma unroll
          for (int r = 0; r < 4; ++r) pk[r] = f2bf(st[qs][t4][r]);
          int c8 = t4 * 2 + (g4 >> 1);
          *(uint2*)&Ps[(w * 32 + qs * 16 + l15) * 64 + ((c8 ^ l7) * 8) + (g4 & 1) * 4] = *(uint2*)pk;
        }
#pragma unroll
        for (int nt = 0; nt < 8; ++nt)
#pragma unroll
          for (int r = 0; r < 4; ++r) o[qs][nt][r] *= a;
      }

#pragma unroll
      for (int ks = 0; ks < 2; ++ks) {
        bf16x8 ap[2];
#pragma unroll
        for (int qs = 0; qs < 2; ++qs)
          ap[qs] = *(const bf16x8*)&Ps[(w * 32 + qs * 16 + l15) * 64 + (((ks * 4 + g4) ^ l7) * 8)];
#pragma unroll
        for (int nt = 0; nt < 8; ++nt) {
          bf16x8 bv = *(const bf16x8*)&VTs[(nt * 16 + l15) * 64 + (((ks * 4 + g4) ^ l7) * 8)];
#pragma unroll
          for (int qs = 0; qs < 2; ++qs)
            o[qs][nt] = __builtin_amdgcn_mfma_f32_16x16x32_bf16(bv, ap[qs], o[qs][nt], 0, 0, 0);
        }
      }
    }

#pragma unroll
    for (int qs = 0; qs < 2; ++qs) {
      if (q0 + w * 32 + qs * 16 < 16) continue;   // rows 0-15 written by global path
      const int q = q0 + w * 32 + qs * 16 + l15;
      const float inv = 1.f / l_run[qs];
#pragma unroll
      for (int nt = 0; nt < 8; ++nt) {
        u16 pk[4];
#pragma unroll
        for (int r = 0; r < 4; ++r) pk[r] = f2bf(o[qs][nt][r] * inv);
        *(uint2*)&out[(size_t)q * HID + h * HD + nt * 16 + g4 * 4] = *(uint2*)pk;
      }
    }
    return;
  }

  // ---------------- global-query path (split-KV) ----------------
  {
    u16* Ks = smem;             // [64][136]
    u16* Vs = smem + 8704;      // [64][136]
    const int chunk = blockIdx.x - 32;
    const int t = tid;
    const int q = t >> 4, dg = t & 15;

    float qr[8];
    {
      bf16x8 v = *(const bf16x8*)&qk[(size_t)q * QKW + h * HD + dg * 8];
#pragma unroll
      for (int j = 0; j < 8; ++j) qr[j] = bf2f((u16)v[j]);
    }
    float m_run = -1e30f, l_run = 0.f, o[8] = {};
    const int kvbase = chunk * (SEQ / GQC);

    for (int st = 0; st < (SEQ / GQC) / 64; ++st) {
      const int kv0 = kvbase + st * 64;
      __syncthreads();
#pragma unroll
      for (int p = 0; p < 4; ++p) {
        int f = (t + p * 256) * 8;
        int r = f >> 7, c = f & 127;
        *(uint4*)&Ks[r * 136 + c] = *(const uint4*)&qk[(size_t)(kv0 + r) * QKW + 2048 + h * HD + c];
      }
#pragma unroll
      for (int p = 0; p < 4; ++p) {
        int id = p * 256 + t;
        int d = id >> 3, c8 = id & 7;
        uint4 v = *(const uint4*)&vt[(size_t)h * (HD * SEQ) + (size_t)d * SEQ + kv0 + c8 * 8];
        const u16* pv16 = (const u16*)&v;
#pragma unroll
        for (int j = 0; j < 8; ++j) Vs[(c8 * 8 + j) * 136 + d] = pv16[j];
      }
      __syncthreads();
      for (int kv = 0; kv < 64; ++kv) {
        bf16x8 kr = *(const bf16x8*)&Ks[kv * 136 + dg * 8];
        float s = 0.f;
#pragma unroll
        for (int j = 0; j < 8; ++j) s += qr[j] * bf2f((u16)kr[j]);
        s += __shfl_xor(s, 1, 64); s += __shfl_xor(s, 2, 64);
        s += __shfl_xor(s, 4, 64); s += __shfl_xor(s, 8, 64);
        s *= SCALE;
        float mnew = fmaxf(m_run, s);
        float alpha = __expf(m_run - mnew);
        float p = __expf(s - mnew);
        m_run = mnew;
        l_run = l_run * alpha + p;
        bf16x8 vr = *(const bf16x8*)&Vs[kv * 136 + dg * 8];
#pragma unroll
        for (int j = 0; j < 8; ++j) o[j] = o[j] * alpha + p * bf2f((u16)vr[j]);
      }
    }
    float* op = &Opart[(((size_t)h * GQC + chunk) * 16 + q) * HD + dg * 8];
#pragma unroll
    for (int j = 0; j < 8; ++j) op[j] = o[j];
    if (dg == 0) {
      float* ml = &MLpart[(((size_t)h * GQC + chunk) * 16 + q) * 2];
      ml[0] = m_run; ml[1] = l_run;
    }

    // last-chunk-done reduction for this head
    __syncthreads();                 // all waves' stores drained (vmcnt 0 before barrier)
    if (t == 0) {
      __threadfence();               // release: flush XCD L2 to coherence point
      lastflag = (atomicAdd(&cnt[h], 1u) == GQC - 1) ? 1u : 0u;
    }
    __syncthreads();
    if (lastflag) {
      __threadfence();               // acquire: invalidate stale cached partials
      float M = -1e30f;
      for (int c = 0; c < GQC; ++c)
        M = fmaxf(M, MLpart[(((size_t)h * GQC + c) * 16 + q) * 2]);
      float L = 0.f, oo[8] = {};
      for (int c = 0; c < GQC; ++c) {
        const float* ml = &MLpart[(((size_t)h * GQC + c) * 16 + q) * 2];
        float e = __expf(ml[0] - M);
        L += e * ml[1];
        const float* opc = &Opart[(((size_t)h * GQC + c) * 16 + q) * HD + dg * 8];
#pragma unroll
        for (int j = 0; j < 8; ++j) oo[j] += e * opc[j];
      }
      float inv = 1.f / L;
      u16 tmp[8];
#pragma unroll
      for (int j = 0; j < 8; ++j) tmp[j] = f2bf(oo[j] * inv);
      *(uint4*)&out[(size_t)q * HID + h * HD + dg * 8] = *(uint4*)tmp;
    }
  }
}

extern "C" void kernel_launch(void* const* d_in, const int* in_sizes, int n_in,
                              void* d_out, int out_size, void* d_ws, size_t ws_size,
                              hipStream_t stream) {
  const float* X  = (const float*)d_in[0];
  const float* Wq = (const float*)d_in[1];
  const float* Wk = (const float*)d_in[2];
  const float* Wv = (const float*)d_in[3];
  const float* Wo = (const float*)d_in[4];
  float* out = (float*)d_out;

  // workspace layout (96 MiB, lifetime-aliased):
  //  [0,16M):   Xbf   (dead after QKV GEMM)
  //  [16M,40M): Wcat  (dead after QKV GEMM) -> [16M,32M) AttnO, [32M,36M) Opart,
  //                                            [36M,36M+64K) MLpart
  //  [40M,72M): QK row-major [4096][4096] bf16 (Q | K)
  //  [72M,88M): VT[h][d][s] bf16 (written directly by QKV GEMM epilogue)
  //  [88M,96M): Wo^T bf16
  //  cnt -> first 64 B of d_out (untouched until final GEMM overwrites it).
  char* ws = (char*)d_ws;
  u16* Xbf    = (u16*)(ws);
  u16* Wcat   = (u16*)(ws + (size_t)(16 << 20));
  u16* AttnO  = (u16*)(ws + (size_t)(16 << 20));     // alias Wcat (post-GEMM)
  float* Opart  = (float*)(ws + (size_t)(32 << 20));
  float* MLpart = (float*)(ws + (size_t)(36 << 20));
  unsigned* cnt = (unsigned*)d_out;
  u16* QK     = (u16*)(ws + (size_t)(40 << 20));
  u16* VT     = (u16*)(ws + (size_t)(72 << 20));
  u16* Wot    = (u16*)(ws + (size_t)(88 << 20));

  // 1) prep: X->bf16, weight transposes, counter zero (one dispatch)
  prep<<<dim3(12288), 256, 0, stream>>>(X, Wq, Wk, Wv, Wo, Xbf, Wcat, Wot, cnt);
  // 2) fused QKV GEMM (256x256 8-phase read-ahead): Q,K -> QK; V -> VT
  gemm256<u16, true><<<dim3(24, 16), 512, 0, stream>>>(Xbf, Wcat, QK, VT, HID, QKW);
  // 3) fused attention: local flash + global-query split-KV + last-block reduce
  attn_fused<<<dim3(32 + GQC, NH), 256, 0, stream>>>(QK, VT, AttnO, Opart, MLpart, cnt);
  // 4) output projection -> fp32 out (overwrites cnt bytes with real output)
  gemm_bt<float, false><<<dim3(16, 32), 256, 0, stream>>>(AttnO, Wot, out, nullptr, HID, HID);
}

// Round 5
// 404.578 us; speedup vs baseline: 1.0381x; 1.0381x over previous
//
#include <hip/hip_runtime.h>
#include <stdint.h>

#define SEQ    4096
#define HID    2048
#define NQKV   6144
#define QKW    4096   // width of the QK row-major buffer (Q | K)
#define NH     16
#define HD     128
#define SCALE  0.08838834764831845f
#define GQC    32     // split-KV chunks for global-query path (128 kv each)

typedef unsigned short u16;
typedef __attribute__((ext_vector_type(8))) short bf16x8;
typedef __attribute__((ext_vector_type(4))) float f32x4;

__device__ __forceinline__ u16 f2bf(float f) {
  union { float f; unsigned u; } v; v.f = f;
  unsigned r = v.u + 0x7FFFu + ((v.u >> 16) & 1u);
  return (u16)(r >> 16);
}

__device__ __forceinline__ float bf2f(u16 b) {
  union { unsigned u; float f; } c; c.u = ((unsigned)b) << 16; return c.f;
}

__device__ __forceinline__ void async16(const u16* g, u16* l) {
  __builtin_amdgcn_global_load_lds(
      (const __attribute__((address_space(1))) unsigned int*)g,
      (__attribute__((address_space(3))) unsigned int*)l, 16, 0, 0);
}

// ---------------- prep: X->bf16 convert + 4 weight transposes + counter zero ----------------
// 1-D grid: [0, 8192) cvt blocks, [8192, 12288) transpose blocks.
// cnt lives in d_out (NOT ws): ws is exactly full; d_out untouched until the
// final out-projection overwrites it entirely.
__global__ __launch_bounds__(256) void prep(const float* __restrict__ X,
                                            const float* __restrict__ W0,
                                            const float* __restrict__ W1,
                                            const float* __restrict__ W2,
                                            const float* __restrict__ W3,
                                            u16* __restrict__ Xbf,
                                            u16* __restrict__ Wcat,
                                            u16* __restrict__ Wot,
                                            unsigned* __restrict__ cnt) {
  const int bx = blockIdx.x;
  const int t = threadIdx.x;
  if (bx == 0 && t < NH) cnt[t] = 0u;     // zero split-K completion counters
  if (bx < 8192) {
    int i = bx * 256 + t;
    float4 v = ((const float4*)X)[i];
    ushort4 o;
    o.x = f2bf(v.x); o.y = f2bf(v.y); o.z = f2bf(v.z); o.w = f2bf(v.w);
    ((ushort4*)Xbf)[i] = o;
    return;
  }
  __shared__ __align__(16) u16 Ts[64 * 68];
  const int b = bx - 8192;
  const int z = b >> 10;
  const int k0 = ((b >> 5) & 31) * 64;
  const int n0 = (b & 31) * 64;
  const float* W = (z == 0) ? W0 : (z == 1) ? W1 : (z == 2) ? W2 : W3;
  u16* Wt = (z < 3) ? (Wcat + (size_t)z * 2048 * 2048) : Wot;
#pragma unroll
  for (int p = 0; p < 4; ++p) {
    int f = (t + p * 256) * 4;
    int r = f >> 6, c = f & 63;            // r=k_local, c=n_local
    float4 v = *(const float4*)&W[(size_t)(k0 + r) * 2048 + n0 + c];
    ushort4 o; o.x = f2bf(v.x); o.y = f2bf(v.y); o.z = f2bf(v.z); o.w = f2bf(v.w);
    *(ushort4*)&Ts[r * 68 + c] = o;
  }
  __syncthreads();
#pragma unroll
  for (int p = 0; p < 4; ++p) {
    int g = (t + p * 256) * 4;
    int r = g >> 6, c = g & 63;            // r=n_local, c=k_local
    ushort4 o;
    o.x = Ts[(c + 0) * 68 + r];
    o.y = Ts[(c + 1) * 68 + r];
    o.z = Ts[(c + 2) * 68 + r];
    o.w = Ts[(c + 3) * 68 + r];
    *(ushort4*)&Wt[(size_t)(n0 + r) * 2048 + k0 + c] = o;
  }
}

// ---------------- 128x128 GEMM, m97 structure + R5 LDS slot-swizzle ----------------
// R5: the 8-phase 256^2 ports (R2/R3/R4) all landed BELOW this kernel (27-33%
// vs 36.5% MfmaUtil) — they run 1 block/CU and lose the multi-block wave
// overlap (m114) that makes this kernel's barrier drains cheap. Reverted.
// This round's change: kill the measured 1.26e7 LDS bank-conflict cycles
// (~16% of dispatch time). [row][32] fragment reads are ~4-way conflicted
// (64B rows: r and r+2 alias banks). Swizzle 16B slots: logical slot s lives
// at physical s ^ ((row>>1)&3); residual 2-way aliasing is free (m136).
// Applied via rule 21: LDS stays linear for global_load_lds; the INVERSE
// permutation goes on the per-lane global source column:
//   scol = ((lane&3) ^ ((lane>>3)&3)) * 8      (wid*32 term cancels: %4 == 0)
// and fragment reads XOR the slot with ((l15>>1)&3) (row bits below 16 only;
// wm*64 / i*16 terms cancel). Same mechanism measured 0 conflicts in R2-R4.
template <typename OutT, bool WVT>
__global__ __launch_bounds__(256) void gemm_bt(const u16* __restrict__ A,
                                               const u16* __restrict__ B,
                                               OutT* __restrict__ C,
                                               u16* __restrict__ VTout,
                                               int K, int ldc) {
  __shared__ __align__(16) u16 As0[128 * 32];
  __shared__ __align__(16) u16 As1[128 * 32];
  __shared__ __align__(16) u16 Bs0[128 * 32];
  __shared__ __align__(16) u16 Bs1[128 * 32];
  const int m0 = blockIdx.y * 128;
  const int n0 = blockIdx.x * 128;
  const int tid = threadIdx.x;
  const int wid = tid >> 6;
  const int lane = tid & 63;
  const int wm = wid & 1, wn = wid >> 1;
  const int l15 = lane & 15, g4 = lane >> 4;

  const int srow = wid * 32 + (lane >> 2);
  // R5 swizzle: physical slot (lane&3) holds logical slot (lane&3)^f(row),
  // f(row) = (row>>1)&3; for srow rows, f = ((lane>>2)>>1)&3 = (lane>>3)&3.
  const int scol = ((lane & 3) ^ ((lane >> 3) & 3)) * 8;
  // fragment-read column swizzle: f(l15-rows) = (l15>>1)&3, constant per lane
  const int fsw = (l15 >> 1) & 3;

  f32x4 acc[4][4] = {};

  const u16* pa0 = &A[(size_t)(m0 + srow) * K + scol];
  const u16* pa1 = &A[(size_t)(m0 + srow + 16) * K + scol];
  const u16* pb0 = &B[(size_t)(n0 + srow) * K + scol];
  const u16* pb1 = &B[(size_t)(n0 + srow + 16) * K + scol];
  const int lo0 = (wid * 32) * 32, lo1 = (wid * 32 + 16) * 32;

  for (int kt = 0; kt < K; kt += 64) {
    __syncthreads();
    async16(pa0 + kt, &As0[lo0]);
    async16(pa1 + kt, &As0[lo1]);
    async16(pb0 + kt, &Bs0[lo0]);
    async16(pb1 + kt, &Bs0[lo1]);
    async16(pa0 + kt + 32, &As1[lo0]);
    async16(pa1 + kt + 32, &As1[lo1]);
    async16(pb0 + kt + 32, &Bs1[lo0]);
    async16(pb1 + kt + 32, &Bs1[lo1]);
    __syncthreads();
    {
      bf16x8 af[4], bfr[4];
#pragma unroll
      for (int i = 0; i < 4; ++i)
        af[i] = *(const bf16x8*)&As0[(wm * 64 + i * 16 + l15) * 32 + ((g4 ^ fsw) * 8)];
#pragma unroll
      for (int i = 0; i < 4; ++i)
        bfr[i] = *(const bf16x8*)&Bs0[(wn * 64 + i * 16 + l15) * 32 + ((g4 ^ fsw) * 8)];
#pragma unroll
      for (int mi = 0; mi < 4; ++mi)
#pragma unroll
        for (int ni = 0; ni < 4; ++ni)
          acc[mi][ni] = __builtin_amdgcn_mfma_f32_16x16x32_bf16(af[mi], bfr[ni], acc[mi][ni], 0, 0, 0);
    }
    {
      bf16x8 af[4], bfr[4];
#pragma unroll
      for (int i = 0; i < 4; ++i)
        af[i] = *(const bf16x8*)&As1[(wm * 64 + i * 16 + l15) * 32 + ((g4 ^ fsw) * 8)];
#pragma unroll
      for (int i = 0; i < 4; ++i)
        bfr[i] = *(const bf16x8*)&Bs1[(wn * 64 + i * 16 + l15) * 32 + ((g4 ^ fsw) * 8)];
#pragma unroll
      for (int mi = 0; mi < 4; ++mi)
#pragma unroll
        for (int ni = 0; ni < 4; ++ni)
          acc[mi][ni] = __builtin_amdgcn_mfma_f32_16x16x32_bf16(af[mi], bfr[ni], acc[mi][ni], 0, 0, 0);
    }
  }

  // C/D layout (m89): col = lane&15, row = (lane>>4)*4 + reg
  if (WVT && n0 >= QKW) {
#pragma unroll
    for (int mi = 0; mi < 4; ++mi)
#pragma unroll
      for (int ni = 0; ni < 4; ++ni) {
        const int nv = n0 - QKW + wn * 64 + ni * 16 + l15;
        const int hh = nv >> 7, dd = nv & 127;
        u16* base = &VTout[((size_t)hh * HD + dd) * SEQ];
        const int mb = m0 + wm * 64 + mi * 16 + g4 * 4;
        u16 pk[4];
#pragma unroll
        for (int r = 0; r < 4; ++r) pk[r] = f2bf(acc[mi][ni][r]);
        *(uint2*)&base[mb] = *(uint2*)pk;
      }
  } else {
#pragma unroll
    for (int mi = 0; mi < 4; ++mi)
#pragma unroll
      for (int ni = 0; ni < 4; ++ni) {
        const int n = n0 + wn * 64 + ni * 16 + l15;
#pragma unroll
        for (int r = 0; r < 4; ++r) {
          const int m = m0 + wm * 64 + mi * 16 + g4 * 4 + r;
          float v = acc[mi][ni][r];
          if constexpr (sizeof(OutT) == 2) {
            C[(size_t)m * ldc + n] = (OutT)f2bf(v);
          } else {
            C[(size_t)m * ldc + n] = v;
          }
        }
      }
  }
}

// ---------------- fused attention dispatch ----------------
// blockIdx.x < 32 : local 128-q flash blocks (window + global-kv), write rows 16..4095.
// blockIdx.x >= 32: split-KV chunk for global queries (q<16); the LAST chunk to
//                   finish per head reduces all partials and writes rows 0..15.
__global__ __launch_bounds__(256, 2) void attn_fused(const u16* __restrict__ qk,
                                                     const u16* __restrict__ vt,
                                                     u16* __restrict__ out,
                                                     float* __restrict__ Opart,
                                                     float* __restrict__ MLpart,
                                                     unsigned* __restrict__ cnt) {
  __shared__ __align__(16) u16 smem[24576];   // 48 KB, overlaid per path
  __shared__ unsigned lastflag;
  const int h = blockIdx.y;
  const int tid = threadIdx.x;
  const int lane = tid & 63;

  if (blockIdx.x < 32) {
    // ---------------- local path ----------------
    u16* Ks  = smem;            // [64 kv][128 d] swizzled, 16 KB
    u16* VTs = smem + 8192;     // [128 d][64 kv] swizzled, 16 KB
    u16* Ps  = smem + 16384;    // [128 q][64 kv] swizzled, wave-private rows, 16 KB
    const int q0 = blockIdx.x * 128;
    const int w = tid >> 6;
    const int l15 = lane & 15, g4 = lane >> 4, l7 = lane & 7;

    bf16x8 qf[2][4];
#pragma unroll
    for (int qs = 0; qs < 2; ++qs) {
      const u16* qrow = &qk[(size_t)(q0 + w * 32 + qs * 16 + l15) * QKW + h * HD + g4 * 8];
#pragma unroll
      for (int kk = 0; kk < 4; ++kk) qf[qs][kk] = *(const bf16x8*)&qrow[kk * 32];
    }

    float m_run[2] = {-1e30f, -1e30f}, l_run[2] = {0.f, 0.f};
    f32x4 o[2][8] = {};

    int lo = q0 - 255;
    int lo_blk = (lo < 0) ? 0 : (lo >> 6);
    int hi_blk = (q0 + 382) >> 6;
    if (hi_blk > 63) hi_blk = 63;
    const int extra = (lo_blk > 0) ? 1 : 0;
    const int nsteps = hi_blk - lo_blk + 1 + extra;

    for (int step = 0; step < nsteps; ++step) {
      const int kb = (extra && step == 0) ? 0 : (lo_blk + step - extra);
      const int kv0 = kb * 64;
      __syncthreads();
#pragma unroll
      for (int p = 0; p < 4; ++p) {
        const int r = w * 16 + p * 4 + (lane >> 4);
        const u16* src = &qk[(size_t)(kv0 + r) * QKW + 2048 + h * HD + (((lane & 15) ^ (r & 15)) * 8)];
        async16(src, &Ks[(w * 16 + p * 4) * 128]);
      }
#pragma unroll
      for (int p = 0; p < 4; ++p) {
        const int r = w * 32 + p * 8 + (lane >> 3);
        const u16* src = &vt[(size_t)h * (HD * SEQ) + (size_t)r * SEQ + kv0 + (((lane & 7) ^ (r & 7)) * 8)];
        async16(src, &VTs[(w * 32 + p * 8) * 64]);
      }
      __syncthreads();

      f32x4 st[2][4] = {};
#pragma unroll
      for (int kk = 0; kk < 4; ++kk) {
        bf16x8 ak[4];
#pragma unroll
        for (int t4 = 0; t4 < 4; ++t4)
          ak[t4] = *(const bf16x8*)&Ks[(t4 * 16 + l15) * 128 + (((kk * 4 + g4) ^ l15) * 8)];
#pragma unroll
        for (int qs = 0; qs < 2; ++qs)
#pragma unroll
          for (int t4 = 0; t4 < 4; ++t4)
            st[qs][t4] = __builtin_amdgcn_mfma_f32_16x16x32_bf16(ak[t4], qf[qs][kk], st[qs][t4], 0, 0, 0);
      }

#pragma unroll
      for (int qs = 0; qs < 2; ++qs) {
        const int q = q0 + w * 32 + qs * 16 + l15;
        float cmax = -1e30f;
#pragma unroll
        for (int t4 = 0; t4 < 4; ++t4)
#pragma unroll
          for (int r = 0; r < 4; ++r) {
            int kv = kv0 + t4 * 16 + g4 * 4 + r;
            int dq = q - kv; if (dq < 0) dq = -dq;
            bool ok = (dq < 256) || (kv < 16);
            float s = ok ? st[qs][t4][r] * SCALE : -1e30f;
            st[qs][t4][r] = s;
            cmax = fmaxf(cmax, s);
          }
        cmax = fmaxf(cmax, __shfl_xor(cmax, 16, 64));
        cmax = fmaxf(cmax, __shfl_xor(cmax, 32, 64));
        float mnew = fmaxf(m_run[qs], cmax);
        float csum = 0.f;
#pragma unroll
        for (int t4 = 0; t4 < 4; ++t4)
#pragma unroll
          for (int r = 0; r < 4; ++r) {
            float p = __expf(st[qs][t4][r] - mnew);
            st[qs][t4][r] = p;
            csum += p;
          }
        csum += __shfl_xor(csum, 16, 64);
        csum += __shfl_xor(csum, 32, 64);
        float a = __expf(m_run[qs] - mnew);
        m_run[qs] = mnew;
        l_run[qs] = l_run[qs] * a + csum;

#pragma unroll
        for (int t4 = 0; t4 < 4; ++t4) {
          u16 pk[4];
#pragma unroll
          for (int r = 0; r < 4; ++r) pk[r] = f2bf(st[qs][t4][r]);
          int c8 = t4 * 2 + (g4 >> 1);
          *(uint2*)&Ps[(w * 32 + qs * 16 + l15) * 64 + ((c8 ^ l7) * 8) + (g4 & 1) * 4] = *(uint2*)pk;
        }
#pragma unroll
        for (int nt = 0; nt < 8; ++nt)
#pragma unroll
          for (int r = 0; r < 4; ++r) o[qs][nt][r] *= a;
      }

#pragma unroll
      for (int ks = 0; ks < 2; ++ks) {
        bf16x8 ap[2];
#pragma unroll
        for (int qs = 0; qs < 2; ++qs)
          ap[qs] = *(const bf16x8*)&Ps[(w * 32 + qs * 16 + l15) * 64 + (((ks * 4 + g4) ^ l7) * 8)];
#pragma unroll
        for (int nt = 0; nt < 8; ++nt) {
          bf16x8 bv = *(const bf16x8*)&VTs[(nt * 16 + l15) * 64 + (((ks * 4 + g4) ^ l7) * 8)];
#pragma unroll
          for (int qs = 0; qs < 2; ++qs)
            o[qs][nt] = __builtin_amdgcn_mfma_f32_16x16x32_bf16(bv, ap[qs], o[qs][nt], 0, 0, 0);
        }
      }
    }

#pragma unroll
    for (int qs = 0; qs < 2; ++qs) {
      if (q0 + w * 32 + qs * 16 < 16) continue;   // rows 0-15 written by global path
      const int q = q0 + w * 32 + qs * 16 + l15;
      const float inv = 1.f / l_run[qs];
#pragma unroll
      for (int nt = 0; nt < 8; ++nt) {
        u16 pk[4];
#pragma unroll
        for (int r = 0; r < 4; ++r) pk[r] = f2bf(o[qs][nt][r] * inv);
        *(uint2*)&out[(size_t)q * HID + h * HD + nt * 16 + g4 * 4] = *(uint2*)pk;
      }
    }
    return;
  }

  // ---------------- global-query path (split-KV) ----------------
  {
    u16* Ks = smem;             // [64][136]
    u16* Vs = smem + 8704;      // [64][136]
    const int chunk = blockIdx.x - 32;
    const int t = tid;
    const int q = t >> 4, dg = t & 15;

    float qr[8];
    {
      bf16x8 v = *(const bf16x8*)&qk[(size_t)q * QKW + h * HD + dg * 8];
#pragma unroll
      for (int j = 0; j < 8; ++j) qr[j] = bf2f((u16)v[j]);
    }
    float m_run = -1e30f, l_run = 0.f, o[8] = {};
    const int kvbase = chunk * (SEQ / GQC);

    for (int st = 0; st < (SEQ / GQC) / 64; ++st) {
      const int kv0 = kvbase + st * 64;
      __syncthreads();
#pragma unroll
      for (int p = 0; p < 4; ++p) {
        int f = (t + p * 256) * 8;
        int r = f >> 7, c = f & 127;
        *(uint4*)&Ks[r * 136 + c] = *(const uint4*)&qk[(size_t)(kv0 + r) * QKW + 2048 + h * HD + c];
      }
#pragma unroll
      for (int p = 0; p < 4; ++p) {
        int id = p * 256 + t;
        int d = id >> 3, c8 = id & 7;
        uint4 v = *(const uint4*)&vt[(size_t)h * (HD * SEQ) + (size_t)d * SEQ + kv0 + c8 * 8];
        const u16* pv16 = (const u16*)&v;
#pragma unroll
        for (int j = 0; j < 8; ++j) Vs[(c8 * 8 + j) * 136 + d] = pv16[j];
      }
      __syncthreads();
      for (int kv = 0; kv < 64; ++kv) {
        bf16x8 kr = *(const bf16x8*)&Ks[kv * 136 + dg * 8];
        float s = 0.f;
#pragma unroll
        for (int j = 0; j < 8; ++j) s += qr[j] * bf2f((u16)kr[j]);
        s += __shfl_xor(s, 1, 64); s += __shfl_xor(s, 2, 64);
        s += __shfl_xor(s, 4, 64); s += __shfl_xor(s, 8, 64);
        s *= SCALE;
        float mnew = fmaxf(m_run, s);
        float alpha = __expf(m_run - mnew);
        float p = __expf(s - mnew);
        m_run = mnew;
        l_run = l_run * alpha + p;
        bf16x8 vr = *(const bf16x8*)&Vs[kv * 136 + dg * 8];
#pragma unroll
        for (int j = 0; j < 8; ++j) o[j] = o[j] * alpha + p * bf2f((u16)vr[j]);
      }
    }
    float* op = &Opart[(((size_t)h * GQC + chunk) * 16 + q) * HD + dg * 8];
#pragma unroll
    for (int j = 0; j < 8; ++j) op[j] = o[j];
    if (dg == 0) {
      float* ml = &MLpart[(((size_t)h * GQC + chunk) * 16 + q) * 2];
      ml[0] = m_run; ml[1] = l_run;
    }

    // last-chunk-done reduction for this head
    __syncthreads();                 // all waves' stores drained (vmcnt 0 before barrier)
    if (t == 0) {
      __threadfence();               // release: flush XCD L2 to coherence point
      lastflag = (atomicAdd(&cnt[h], 1u) == GQC - 1) ? 1u : 0u;
    }
    __syncthreads();
    if (lastflag) {
      __threadfence();               // acquire: invalidate stale cached partials
      float M = -1e30f;
      for (int c = 0; c < GQC; ++c)
        M = fmaxf(M, MLpart[(((size_t)h * GQC + c) * 16 + q) * 2]);
      float L = 0.f, oo[8] = {};
      for (int c = 0; c < GQC; ++c) {
        const float* ml = &MLpart[(((size_t)h * GQC + c) * 16 + q) * 2];
        float e = __expf(ml[0] - M);
        L += e * ml[1];
        const float* opc = &Opart[(((size_t)h * GQC + c) * 16 + q) * HD + dg * 8];
#pragma unroll
        for (int j = 0; j < 8; ++j) oo[j] += e * opc[j];
      }
      float inv = 1.f / L;
      u16 tmp[8];
#pragma unroll
      for (int j = 0; j < 8; ++j) tmp[j] = f2bf(oo[j] * inv);
      *(uint4*)&out[(size_t)q * HID + h * HD + dg * 8] = *(uint4*)tmp;
    }
  }
}

extern "C" void kernel_launch(void* const* d_in, const int* in_sizes, int n_in,
                              void* d_out, int out_size, void* d_ws, size_t ws_size,
                              hipStream_t stream) {
  const float* X  = (const float*)d_in[0];
  const float* Wq = (const float*)d_in[1];
  const float* Wk = (const float*)d_in[2];
  const float* Wv = (const float*)d_in[3];
  const float* Wo = (const float*)d_in[4];
  float* out = (float*)d_out;

  // workspace layout (96 MiB, lifetime-aliased):
  //  [0,16M):   Xbf   (dead after QKV GEMM)
  //  [16M,40M): Wcat  (dead after QKV GEMM) -> [16M,32M) AttnO, [32M,36M) Opart,
  //                                            [36M,36M+64K) MLpart
  //  [40M,72M): QK row-major [4096][4096] bf16 (Q | K)
  //  [72M,88M): VT[h][d][s] bf16 (written directly by QKV GEMM epilogue)
  //  [88M,96M): Wo^T bf16
  //  cnt -> first 64 B of d_out (untouched until final GEMM overwrites it).
  char* ws = (char*)d_ws;
  u16* Xbf    = (u16*)(ws);
  u16* Wcat   = (u16*)(ws + (size_t)(16 << 20));
  u16* AttnO  = (u16*)(ws + (size_t)(16 << 20));     // alias Wcat (post-GEMM)
  float* Opart  = (float*)(ws + (size_t)(32 << 20));
  float* MLpart = (float*)(ws + (size_t)(36 << 20));
  unsigned* cnt = (unsigned*)d_out;
  u16* QK     = (u16*)(ws + (size_t)(40 << 20));
  u16* VT     = (u16*)(ws + (size_t)(72 << 20));
  u16* Wot    = (u16*)(ws + (size_t)(88 << 20));

  // 1) prep: X->bf16, weight transposes, counter zero (one dispatch)
  prep<<<dim3(12288), 256, 0, stream>>>(X, Wq, Wk, Wv, Wo, Xbf, Wcat, Wot, cnt);
  // 2) fused QKV GEMM (128^2 m97 + slot swizzle): Q,K -> QK; V -> VT
  gemm_bt<u16, true><<<dim3(48, 32), 256, 0, stream>>>(Xbf, Wcat, QK, VT, HID, QKW);
  // 3) fused attention: local flash + global-query split-KV + last-block reduce
  attn_fused<<<dim3(32 + GQC, NH), 256, 0, stream>>>(QK, VT, AttnO, Opart, MLpart, cnt);
  // 4) output projection -> fp32 out (overwrites cnt bytes with real output)
  gemm_bt<float, false><<<dim3(16, 32), 256, 0, stream>>>(AttnO, Wot, out, nullptr, HID, HID);
}